// Round 3
// baseline (286.622 us; speedup 1.0000x reference)
//
#include <hip/hip_runtime.h>

#define BATCH 16
#define CIN   64
#define HW    128
#define OC    128
#define KSIZE 576   // 64 * 9

typedef float float4v __attribute__((ext_vector_type(4)));
typedef int   int4v   __attribute__((ext_vector_type(4)));
typedef unsigned int uint;

// workspace layout (float offsets)
#define WS_ACT   0      // act_scale[576], k = c*9 + r order
#define WS_WSC   576    // weight_scale[576]
#define WS_XMUL  1152   // xmul[r*64+c] = 1/(scale[c*9+r]*s_x)
#define WS_SXSW  1728
#define WS_WQ_BYTE_OFF 8192   // int8 wq_s[9][128][64], frags XOR-pre-swizzled

#define SWZ(x) ((((x) & 3) ^ (((x) >> 2) & 3)))

__device__ __forceinline__ void async_cp16(const void* g, void* l) {
    __builtin_amdgcn_global_load_lds(
        (const __attribute__((address_space(1))) unsigned int*)g,
        (__attribute__((address_space(3))) unsigned int*)l, 16, 0, 0);
}

// ---------------------------------------------------------------------------
// Kernel 1: fused absmax (unchanged from R2 — passed).
// ---------------------------------------------------------------------------
__global__ __launch_bounds__(256) void k_absmax(const float* __restrict__ in,
                                                const float* __restrict__ w,
                                                float* __restrict__ wsf) {
    const int tid = threadIdx.x, lane = tid & 63, wid = tid >> 6;
    if (blockIdx.x < 1024) {
        const int c = blockIdx.x >> 4, bs = blockIdx.x & 15;
        const float4v* p = (const float4v*)(in + (size_t)(bs * CIN + c) * (HW * HW));
        float m[9];
#pragma unroll
        for (int i = 0; i < 9; ++i) m[i] = 0.f;
        for (int e = tid; e < 4096; e += 256) {
            const int h = e >> 5, q = e & 31;
            const float4v v = p[e];
            const float a0 = fabsf(v[0]), a1 = fabsf(v[1]), a2 = fabsf(v[2]), a3 = fabsf(v[3]);
            const float m01 = fmaxf(a0, a1), m12 = fmaxf(a1, a2);
            const float mall = fmaxf(m01, fmaxf(a2, a3));
            const float mw0 = (q == 31) ? fmaxf(m01, a2) : mall;
            const float mw2 = (q == 0)  ? fmaxf(m12, a3) : mall;
            const bool h0 = (h <= 126), h2 = (h >= 1);
            m[0] = fmaxf(m[0], h0 ? mw0 : 0.f);
            m[1] = fmaxf(m[1], h0 ? mall : 0.f);
            m[2] = fmaxf(m[2], h0 ? mw2 : 0.f);
            m[3] = fmaxf(m[3], mw0);
            m[4] = fmaxf(m[4], mall);
            m[5] = fmaxf(m[5], mw2);
            m[6] = fmaxf(m[6], h2 ? mw0 : 0.f);
            m[7] = fmaxf(m[7], h2 ? mall : 0.f);
            m[8] = fmaxf(m[8], h2 ? mw2 : 0.f);
        }
#pragma unroll
        for (int i = 0; i < 9; ++i)
            for (int off = 32; off; off >>= 1)
                m[i] = fmaxf(m[i], __shfl_down(m[i], off));
        __shared__ float sred[4][9];
        if (lane == 0)
#pragma unroll
            for (int i = 0; i < 9; ++i) sred[wid][i] = m[i];
        __syncthreads();
        if (tid < 9) {
            float mm = fmaxf(fmaxf(sred[0][tid], sred[1][tid]),
                             fmaxf(sred[2][tid], sred[3][tid]));
            atomicMax((int*)(wsf + WS_ACT + c * 9 + tid), __float_as_int(mm));
        }
    } else {
        const int k = (blockIdx.x - 1024) * 4 + wid;
        float m = fmaxf(fabsf(w[lane * KSIZE + k]), fabsf(w[(lane + 64) * KSIZE + k]));
        for (int off = 32; off; off >>= 1) m = fmaxf(m, __shfl_down(m, off));
        if (lane == 0) wsf[WS_WSC + k] = m;
    }
}

// ---------------------------------------------------------------------------
// Kernel 2: redundant per-block scale + weight quantize -> int8, pre-swizzled
// global layout: wq_s[r][o][ (fc ^ SWZ(o))*16 + (c&15) ], fc = c>>4.
// ---------------------------------------------------------------------------
__global__ __launch_bounds__(576) void k_scale_wq(const float* __restrict__ w,
                                                  float* __restrict__ wsf,
                                                  char* __restrict__ wq_s) {
    __shared__ float ls[576];
    __shared__ float redA[9], redB[9];
    const int t = threadIdx.x, o = blockIdx.x;
    const int lane = t & 63, wid = t >> 6;
    const float a = wsf[WS_ACT + t];
    const float wv = wsf[WS_WSC + t];
    float s = sqrtf(a) / sqrtf(wv);
    if (s == 0.f) s = 1.f;
    ls[t] = s;
    float v1 = a / s;
    float v2 = wv * s;
    for (int off = 32; off; off >>= 1) {
        v1 = fmaxf(v1, __shfl_down(v1, off));
        v2 = fmaxf(v2, __shfl_down(v2, off));
    }
    if (lane == 0) { redA[wid] = v1; redB[wid] = v2; }
    __syncthreads();
    float ax = redA[0], aw = redB[0];
#pragma unroll
    for (int i = 1; i < 9; ++i) { ax = fmaxf(ax, redA[i]); aw = fmaxf(aw, redB[i]); }
    const float sx = ax > 0.f ? ax / 127.f : 1.f;
    const float sw = aw > 0.f ? aw / 127.f : 1.f;
    const int r = t >> 6, c = t & 63, ko = c * 9 + r;
    float q = rintf((w[o * KSIZE + ko] * ls[ko]) / sw);
    q = fminf(127.f, fmaxf(-127.f, q));
    const int qi = (int)q;
    const int fc = c >> 4;
    wq_s[r * 8192 + o * 64 + ((fc ^ SWZ(o)) << 4) + (c & 15)] = (char)qi;
    if (o == 0) {
        wsf[WS_XMUL + t] = 1.0f / (ls[ko] * sx);   // [r][c] layout
        if (t == 0) wsf[WS_SXSW] = sx * sw;
    }
}

// ---------------------------------------------------------------------------
// Kernel 3: i8 implicit-GEMM conv, latency-optimized.
// Block tile: M=64 (ow half-row), N=128 (o), K = 9 chunks of 64 (c).
// 256 threads = 4 waves, wave tile 32x64 (acc 8 int4 = 32 AGPR).
// Pipeline per chunk k: [issue A(k+2)->Av regs] [issue B(k+1) DMA]
//   [quant(k+1): Av loaded a FULL interval ago] [MFMA(k)] [barrier].
// One barrier/chunk; A dbuf 2x5KB, B dbuf 2x8KB, xmul 2.3KB = 29KB LDS.
// ---------------------------------------------------------------------------
__global__ __launch_bounds__(256, 4) void k_gemm(const float* __restrict__ in,
                                                 const char* __restrict__ wq_s,
                                                 const float* __restrict__ wsf,
                                                 float* __restrict__ out) {
    __shared__ char A_l[2][64 * 80];    // [ow][c] i8, 80B rows (4 frag slots + pad)
    __shared__ char B_l[2][128 * 64];   // [o][c] i8, frag-swizzled via global layout
    __shared__ float xm_l[576];

    const int tid = threadIdx.x, lane = tid & 63, wave = tid >> 6;
    // XCD swizzle: each XCD owns a 16-row oh band (L2 reuse of input rows).
    const int g = blockIdx.x;
    const int xcd = g & 7, i = g >> 3;
    const int half = i & 1;
    const int oh = xcd * 16 + ((i >> 1) & 15);
    const int b = i >> 5;
    const int ow_base = half * 64;

    const int wm = (wave & 1) * 32, wn = (wave >> 1) * 64;
    const int cg = tid >> 6;            // wave-uniform c-group (16 channels)
    const int lr = tid & 63;            // local dst row (ow - ow_base)
    const int owd = ow_base + lr;

    // stage xmul table once
    for (int idx = tid; idx < 144; idx += 256)
        ((float4v*)xm_l)[idx] = ((const float4v*)(wsf + WS_XMUL))[idx];

    int4v acc[2][4];
#pragma unroll
    for (int mt = 0; mt < 2; ++mt)
#pragma unroll
        for (int nt = 0; nt < 4; ++nt) acc[mt][nt] = (int4v){0, 0, 0, 0};

    float Av[2][16];

    auto issueA = [&](int r, float* dst) {
        const int kh = r / 3, kw = r - 3 * kh;
        int hh = oh + kh - 1;
        int iw = owd - 1 + kw;
        hh = hh < 0 ? 0 : (hh > 127 ? 127 : hh);
        iw = iw < 0 ? 0 : (iw > 127 ? 127 : iw);
        const float* base = in + (((size_t)(b * CIN + cg * 16) * HW + hh) * HW + iw);
#pragma unroll
        for (int j = 0; j < 16; ++j) dst[j] = base[j * (HW * HW)];
    };

    auto issueB = [&](int r, char* Bbuf) {
        const char* src = wq_s + r * 8192 + tid * 16;
        async_cp16(src, Bbuf + tid * 16);
        async_cp16(src + 4096, Bbuf + tid * 16 + 4096);
    };

    auto quant = [&](int r, const float* src, char* Abuf) {
        const int kh = r / 3, kw = r - 3 * kh;
        const int hh = oh + kh - 1, iw = owd - 1 + kw;
        const float vf = (hh >= 0 && hh < HW && iw >= 0 && iw < HW) ? 1.f : 0.f;
        const float* xp = xm_l + r * 64 + cg * 16;   // wave-uniform -> LDS broadcast
        uint dw[4];
#pragma unroll
        for (int d = 0; d < 4; ++d) {
            uint pk = 0;
#pragma unroll
            for (int j2 = 0; j2 < 4; ++j2) {
                const int j = d * 4 + j2;
                float q = rintf(src[j] * (xp[j] * vf));
                q = fminf(127.f, fmaxf(-127.f, q));
                pk |= ((uint)((int)q & 255)) << (8 * j2);
            }
            dw[d] = pk;
        }
        *(uint4*)(Abuf + lr * 80 + ((cg ^ SWZ(lr)) << 4)) =
            make_uint4(dw[0], dw[1], dw[2], dw[3]);
    };

    auto domfma = [&](const char* Abuf, const char* Bbuf) {
        int4v af[2], bf[4];
#pragma unroll
        for (int mt = 0; mt < 2; ++mt) {
            const int ar = wm + mt * 16 + (lane & 15);
            af[mt] = *(const int4v*)(Abuf + ar * 80 + ((((lane >> 4)) ^ SWZ(ar)) << 4));
        }
#pragma unroll
        for (int nt = 0; nt < 4; ++nt) {
            const int br = wn + nt * 16 + (lane & 15);
            bf[nt] = *(const int4v*)(Bbuf + br * 64 + ((((lane >> 4)) ^ SWZ(br)) << 4));
        }
#pragma unroll
        for (int mt = 0; mt < 2; ++mt)
#pragma unroll
            for (int nt = 0; nt < 4; ++nt)
                acc[mt][nt] = __builtin_amdgcn_mfma_i32_16x16x64_i8(
                    af[mt], bf[nt], acc[mt][nt], 0, 0, 0);
    };

    // prologue
    issueA(0, Av[0]);
    issueB(0, B_l[0]);
    issueA(1, Av[1]);
    __syncthreads();           // publishes xm_l; drains A0/A1/B0 (once per block)
    quant(0, Av[0], A_l[0]);
    __syncthreads();           // publishes A_l[0]

    for (int k = 0; k < 9; ++k) {
        const int kb = k & 1;
        if (k < 7) issueA(k + 2, Av[k & 1]);          // full-interval cover
        if (k < 8) issueB(k + 1, B_l[kb ^ 1]);
        if (k < 8) quant(k + 1, Av[(k + 1) & 1], A_l[kb ^ 1]);
        domfma(A_l[kb], B_l[kb]);
        if (k < 8) __syncthreads();
    }

    const float sxsw = wsf[WS_SXSW];
#pragma unroll
    for (int mt = 0; mt < 2; ++mt)
#pragma unroll
        for (int nt = 0; nt < 4; ++nt) {
            const int owp = ow_base + wm + mt * 16 + ((lane >> 4) << 2);
            const int o = wn + nt * 16 + (lane & 15);
            float4v rv;
#pragma unroll
            for (int q = 0; q < 4; ++q) rv[q] = (float)acc[mt][nt][q] * sxsw;
            *(float4v*)(out + ((size_t)(b * OC + o) * HW + oh) * HW + owp) = rv;
        }
}

// ---------------------------------------------------------------------------
extern "C" void kernel_launch(void* const* d_in, const int* in_sizes, int n_in,
                              void* d_out, int out_size, void* d_ws, size_t ws_size,
                              hipStream_t stream) {
    const float* in = (const float*)d_in[0];   // (16, 64, 128, 128) fp32
    const float* wt = (const float*)d_in[1];   // (128, 64, 3, 3) fp32
    float* out = (float*)d_out;                // (16, 128, 128, 128) fp32
    float* wsf = (float*)d_ws;
    char* wq_s = (char*)d_ws + WS_WQ_BYTE_OFF;

    k_absmax<<<dim3(1024 + 144), dim3(256), 0, stream>>>(in, wt, wsf);
    k_scale_wq<<<dim3(128), dim3(576), 0, stream>>>(wt, wsf, wq_s);
    k_gemm<<<dim3(4096), dim3(256), 0, stream>>>(in, wq_s, wsf, out);
}

// Round 4
// 257.222 us; speedup vs baseline: 1.1143x; 1.1143x over previous
//
#include <hip/hip_runtime.h>

#define BATCH 16
#define CIN   64
#define HW    128
#define OC    128
#define KSIZE 576   // 64 * 9

typedef float float4v __attribute__((ext_vector_type(4)));
typedef int   int4v   __attribute__((ext_vector_type(4)));
typedef unsigned int uint;

// workspace layout (float offsets)
#define WS_ACT   0      // act_scale[576], k = c*9 + r order
#define WS_WSC   576    // weight_scale[576]
#define WS_XMUL  1152   // xmul[r*64+c] = 1/(scale[c*9+r]*s_x)
#define WS_SXSW  1728
#define WS_WQ_BYTE_OFF 8192   // int8 wq_s[9][128][64], frags XOR-pre-swizzled

#define SWZ(x) ((((x) & 3) ^ (((x) >> 2) & 3)))
#define MAGIC 12582912.0f   // 1.5 * 2^23: float add => round-half-even int in low mantissa

__device__ __forceinline__ void async_cp16(const void* g, void* l) {
    __builtin_amdgcn_global_load_lds(
        (const __attribute__((address_space(1))) unsigned int*)g,
        (__attribute__((address_space(3))) unsigned int*)l, 16, 0, 0);
}

// ---------------------------------------------------------------------------
// Kernel 1: fused absmax (unchanged — validated R2/R3).
// ---------------------------------------------------------------------------
__global__ __launch_bounds__(256) void k_absmax(const float* __restrict__ in,
                                                const float* __restrict__ w,
                                                float* __restrict__ wsf) {
    const int tid = threadIdx.x, lane = tid & 63, wid = tid >> 6;
    if (blockIdx.x < 1024) {
        const int c = blockIdx.x >> 4, bs = blockIdx.x & 15;
        const float4v* p = (const float4v*)(in + (size_t)(bs * CIN + c) * (HW * HW));
        float m[9];
#pragma unroll
        for (int i = 0; i < 9; ++i) m[i] = 0.f;
        for (int e = tid; e < 4096; e += 256) {
            const int h = e >> 5, q = e & 31;
            const float4v v = p[e];
            const float a0 = fabsf(v[0]), a1 = fabsf(v[1]), a2 = fabsf(v[2]), a3 = fabsf(v[3]);
            const float m01 = fmaxf(a0, a1), m12 = fmaxf(a1, a2);
            const float mall = fmaxf(m01, fmaxf(a2, a3));
            const float mw0 = (q == 31) ? fmaxf(m01, a2) : mall;
            const float mw2 = (q == 0)  ? fmaxf(m12, a3) : mall;
            const bool h0 = (h <= 126), h2 = (h >= 1);
            m[0] = fmaxf(m[0], h0 ? mw0 : 0.f);
            m[1] = fmaxf(m[1], h0 ? mall : 0.f);
            m[2] = fmaxf(m[2], h0 ? mw2 : 0.f);
            m[3] = fmaxf(m[3], mw0);
            m[4] = fmaxf(m[4], mall);
            m[5] = fmaxf(m[5], mw2);
            m[6] = fmaxf(m[6], h2 ? mw0 : 0.f);
            m[7] = fmaxf(m[7], h2 ? mall : 0.f);
            m[8] = fmaxf(m[8], h2 ? mw2 : 0.f);
        }
#pragma unroll
        for (int i = 0; i < 9; ++i)
            for (int off = 32; off; off >>= 1)
                m[i] = fmaxf(m[i], __shfl_down(m[i], off));
        __shared__ float sred[4][9];
        if (lane == 0)
#pragma unroll
            for (int i = 0; i < 9; ++i) sred[wid][i] = m[i];
        __syncthreads();
        if (tid < 9) {
            float mm = fmaxf(fmaxf(sred[0][tid], sred[1][tid]),
                             fmaxf(sred[2][tid], sred[3][tid]));
            atomicMax((int*)(wsf + WS_ACT + c * 9 + tid), __float_as_int(mm));
        }
    } else {
        const int k = (blockIdx.x - 1024) * 4 + wid;
        float m = fmaxf(fabsf(w[lane * KSIZE + k]), fabsf(w[(lane + 64) * KSIZE + k]));
        for (int off = 32; off; off >>= 1) m = fmaxf(m, __shfl_down(m, off));
        if (lane == 0) wsf[WS_WSC + k] = m;
    }
}

// ---------------------------------------------------------------------------
// Kernel 2: scale + weight quantize -> int8, pre-swizzled (unchanged — validated R3).
// wq_s[r][o][(f ^ SWZ(o))*16 + c%16], f = c/16.
// ---------------------------------------------------------------------------
__global__ __launch_bounds__(576) void k_scale_wq(const float* __restrict__ w,
                                                  float* __restrict__ wsf,
                                                  char* __restrict__ wq_s) {
    __shared__ float ls[576];
    __shared__ float redA[9], redB[9];
    const int t = threadIdx.x, o = blockIdx.x;
    const int lane = t & 63, wid = t >> 6;
    const float a = wsf[WS_ACT + t];
    const float wv = wsf[WS_WSC + t];
    float s = sqrtf(a) / sqrtf(wv);
    if (s == 0.f) s = 1.f;
    ls[t] = s;
    float v1 = a / s;
    float v2 = wv * s;
    for (int off = 32; off; off >>= 1) {
        v1 = fmaxf(v1, __shfl_down(v1, off));
        v2 = fmaxf(v2, __shfl_down(v2, off));
    }
    if (lane == 0) { redA[wid] = v1; redB[wid] = v2; }
    __syncthreads();
    float ax = redA[0], aw = redB[0];
#pragma unroll
    for (int i = 1; i < 9; ++i) { ax = fmaxf(ax, redA[i]); aw = fmaxf(aw, redB[i]); }
    const float sx = ax > 0.f ? ax / 127.f : 1.f;
    const float sw = aw > 0.f ? aw / 127.f : 1.f;
    const int r = t >> 6, c = t & 63, ko = c * 9 + r;
    float q = rintf((w[o * KSIZE + ko] * ls[ko]) / sw);
    q = fminf(127.f, fmaxf(-127.f, q));
    const int qi = (int)q;
    const int fc = c >> 4;
    wq_s[r * 8192 + o * 64 + ((fc ^ SWZ(o)) << 4) + (c & 15)] = (char)qi;
    if (o == 0) {
        wsf[WS_XMUL + t] = 1.0f / (ls[ko] * sx);   // [r][c] layout
        if (t == 0) wsf[WS_SXSW] = sx * sw;
    }
}

// ---------------------------------------------------------------------------
// Kernel 3: barrier-free i8 implicit-GEMM conv.
// Block = (b, oh): 512 threads = 8 waves, wave tile 32ow x 64o (acc 32 VGPR).
// ALL of B (9 planes, 72 KB) + xmul staged to LDS in prologue (one barrier).
// K-loop has NO barriers: each wave builds its A-fragments in registers via
// coalesced global loads + magic-number quantize (+v_perm pack), reads B
// fragments from LDS (XOR swizzle -> 0 bank conflicts), issues 8 MFMAs.
// ---------------------------------------------------------------------------
__global__ __launch_bounds__(512, 4) void k_gemm(const float* __restrict__ in,
                                                 const char* __restrict__ wq_s,
                                                 const float* __restrict__ wsf,
                                                 float* __restrict__ out) {
    __shared__ int4v Bl4[4608];        // 73728 B: 9 planes of [o=128][c=64] i8
    __shared__ float xml[576];
    char* Bl = (char*)Bl4;

    const int tid = threadIdx.x, lane = tid & 63, w = tid >> 6;
    // XCD swizzle: each XCD owns a 16-row oh band per batch (L2 input reuse).
    const int xcd = blockIdx.x & 7, idx = blockIdx.x >> 3;
    const int oh = xcd * 16 + (idx & 15);
    const int b = idx >> 4;
    const int wband = (w & 3) * 32, ohalf = (w >> 2) * 64;
    const int l15 = lane & 15, fsel = lane >> 4;

    // ---- prologue staging (only barrier in the kernel) ----
#pragma unroll
    for (int i = 0; i < 9; ++i)
        async_cp16(wq_s + i * 8192 + tid * 16, Bl + i * 8192 + tid * 16);
    if (tid < 144)
        ((float4v*)xml)[tid] = ((const float4v*)(wsf + WS_XMUL))[tid];
    __syncthreads();

    const float* pb = in + (size_t)b * (CIN * HW * HW) + fsel * (16 * HW * HW);

    int4v acc[2][4];
#pragma unroll
    for (int mt = 0; mt < 2; ++mt)
#pragma unroll
        for (int nt = 0; nt < 4; ++nt) acc[mt][nt] = (int4v){0, 0, 0, 0};

#pragma unroll
    for (int r = 0; r < 9; ++r) {
        const int kh = r / 3, kw = r - 3 * kh;
        const int h = oh + kh - 1;
        const int hc = h < 0 ? 0 : (h > 127 ? 127 : h);
        const bool hok = (unsigned)h < 128u;

        // ---- A: coalesced frag-direct loads (lane&15 = ow, lane>>4 = c-chunk) ----
        float v[2][16];
        int iwv[2];
#pragma unroll
        for (int mt = 0; mt < 2; ++mt) {
            const int iw = wband + mt * 16 + l15 + kw - 1;
            iwv[mt] = iw;
            const int iwc = iw < 0 ? 0 : (iw > 127 ? 127 : iw);
            const float* p = pb + hc * HW + iwc;
#pragma unroll
            for (int j = 0; j < 16; ++j) v[mt][j] = p[j * (HW * HW)];
        }
        // ---- per-lane scales (LDS broadcast; same 16 c's for both mt) ----
        const float* xp = xml + r * 64 + (fsel << 4);
        float xm[16];
#pragma unroll
        for (int d = 0; d < 4; ++d) {
            const float4v t = *(const float4v*)(xp + d * 4);
            xm[d * 4 + 0] = t[0]; xm[d * 4 + 1] = t[1];
            xm[d * 4 + 2] = t[2]; xm[d * 4 + 3] = t[3];
        }
        // ---- quantize: mul, med3-clamp, +MAGIC (round-half-even), v_perm pack ----
        int4v af[2];
#pragma unroll
        for (int mt = 0; mt < 2; ++mt) {
            const bool ok = hok && ((unsigned)iwv[mt] < 128u);
            uint pk[4];
#pragma unroll
            for (int d = 0; d < 4; ++d) {
                uint u[4];
#pragma unroll
                for (int j2 = 0; j2 < 4; ++j2) {
                    float t = v[mt][d * 4 + j2] * xm[d * 4 + j2];
                    t = fminf(127.f, fmaxf(-127.f, t));
                    t += MAGIC;                      // low byte = int8 two's complement
                    u[j2] = __float_as_uint(t);
                }
                const uint p01 = __builtin_amdgcn_perm(u[1], u[0], 0x0C0C0400u);
                const uint p23 = __builtin_amdgcn_perm(u[3], u[2], 0x0C0C0400u);
                pk[d] = __builtin_amdgcn_perm(p23, p01, 0x05040100u);
            }
            af[mt] = ok ? (int4v){(int)pk[0], (int)pk[1], (int)pk[2], (int)pk[3]}
                        : (int4v){0, 0, 0, 0};
        }
        // ---- B frags from LDS (conflict-free swizzle) + 8 MFMA ----
#pragma unroll
        for (int nt = 0; nt < 4; ++nt) {
            const int br = ohalf + nt * 16 + l15;
            const int4v bf = *(const int4v*)(Bl + r * 8192 + br * 64 +
                                             ((fsel ^ SWZ(br)) << 4));
            acc[0][nt] = __builtin_amdgcn_mfma_i32_16x16x64_i8(af[0], bf, acc[0][nt], 0, 0, 0);
            acc[1][nt] = __builtin_amdgcn_mfma_i32_16x16x64_i8(af[1], bf, acc[1][nt], 0, 0, 0);
        }
    }

    // ---- epilogue: C/D row=(lane>>4)*4+reg -> ow, col=lane&15 -> o ----
    const float sxsw = wsf[WS_SXSW];
#pragma unroll
    for (int mt = 0; mt < 2; ++mt)
#pragma unroll
        for (int nt = 0; nt < 4; ++nt) {
            const int owp = wband + mt * 16 + (fsel << 2);
            const int o = ohalf + nt * 16 + l15;
            float4v rv;
#pragma unroll
            for (int q = 0; q < 4; ++q) rv[q] = (float)acc[mt][nt][q] * sxsw;
            *(float4v*)(out + ((size_t)(b * OC + o) * HW + oh) * HW + owp) = rv;
        }
}

// ---------------------------------------------------------------------------
extern "C" void kernel_launch(void* const* d_in, const int* in_sizes, int n_in,
                              void* d_out, int out_size, void* d_ws, size_t ws_size,
                              hipStream_t stream) {
    const float* in = (const float*)d_in[0];   // (16, 64, 128, 128) fp32
    const float* wt = (const float*)d_in[1];   // (128, 64, 3, 3) fp32
    float* out = (float*)d_out;                // (16, 128, 128, 128) fp32
    float* wsf = (float*)d_ws;
    char* wq_s = (char*)d_ws + WS_WQ_BYTE_OFF;

    k_absmax<<<dim3(1024 + 144), dim3(256), 0, stream>>>(in, wt, wsf);
    k_scale_wq<<<dim3(128), dim3(576), 0, stream>>>(wt, wsf, wq_s);
    k_gemm<<<dim3(BATCH * HW), dim3(512), 0, stream>>>(in, wq_s, wsf, out);
}

// Round 5
// 224.858 us; speedup vs baseline: 1.2747x; 1.1439x over previous
//
#include <hip/hip_runtime.h>

#define BATCH 16
#define CIN   64
#define HW    128
#define OC    128
#define KSIZE 576   // 64 * 9

typedef float float4v __attribute__((ext_vector_type(4)));
typedef int   int4v   __attribute__((ext_vector_type(4)));
typedef unsigned int uint;

// workspace layout (float offsets)
#define WS_ACT   0      // act_scale[576], k = c*9 + r order
#define WS_WSC   576    // weight_scale[576]
#define WS_XMUL  1152   // xmul[r*64+c] = 1/(scale[c*9+r]*s_x)
#define WS_SXSW  1728
#define WS_WQ_BYTE_OFF 8192   // int8 wq_s[9][128][64], frags XOR-pre-swizzled

#define SWZ(x) ((((x) & 3) ^ (((x) >> 2) & 3)))
#define MAGIC 12582912.0f   // 1.5 * 2^23: fma bias => round-half-even int8 in low byte

__device__ __forceinline__ void async_cp16(const void* g, void* l) {
    __builtin_amdgcn_global_load_lds(
        (const __attribute__((address_space(1))) unsigned int*)g,
        (__attribute__((address_space(3))) unsigned int*)l, 16, 0, 0);
}

// ---------------------------------------------------------------------------
// Kernel 1: fused absmax (unchanged — validated R2-R4).
// ---------------------------------------------------------------------------
__global__ __launch_bounds__(256) void k_absmax(const float* __restrict__ in,
                                                const float* __restrict__ w,
                                                float* __restrict__ wsf) {
    const int tid = threadIdx.x, lane = tid & 63, wid = tid >> 6;
    if (blockIdx.x < 1024) {
        const int c = blockIdx.x >> 4, bs = blockIdx.x & 15;
        const float4v* p = (const float4v*)(in + (size_t)(bs * CIN + c) * (HW * HW));
        float m[9];
#pragma unroll
        for (int i = 0; i < 9; ++i) m[i] = 0.f;
        for (int e = tid; e < 4096; e += 256) {
            const int h = e >> 5, q = e & 31;
            const float4v v = p[e];
            const float a0 = fabsf(v[0]), a1 = fabsf(v[1]), a2 = fabsf(v[2]), a3 = fabsf(v[3]);
            const float m01 = fmaxf(a0, a1), m12 = fmaxf(a1, a2);
            const float mall = fmaxf(m01, fmaxf(a2, a3));
            const float mw0 = (q == 31) ? fmaxf(m01, a2) : mall;
            const float mw2 = (q == 0)  ? fmaxf(m12, a3) : mall;
            const bool h0 = (h <= 126), h2 = (h >= 1);
            m[0] = fmaxf(m[0], h0 ? mw0 : 0.f);
            m[1] = fmaxf(m[1], h0 ? mall : 0.f);
            m[2] = fmaxf(m[2], h0 ? mw2 : 0.f);
            m[3] = fmaxf(m[3], mw0);
            m[4] = fmaxf(m[4], mall);
            m[5] = fmaxf(m[5], mw2);
            m[6] = fmaxf(m[6], h2 ? mw0 : 0.f);
            m[7] = fmaxf(m[7], h2 ? mall : 0.f);
            m[8] = fmaxf(m[8], h2 ? mw2 : 0.f);
        }
#pragma unroll
        for (int i = 0; i < 9; ++i)
            for (int off = 32; off; off >>= 1)
                m[i] = fmaxf(m[i], __shfl_down(m[i], off));
        __shared__ float sred[4][9];
        if (lane == 0)
#pragma unroll
            for (int i = 0; i < 9; ++i) sred[wid][i] = m[i];
        __syncthreads();
        if (tid < 9) {
            float mm = fmaxf(fmaxf(sred[0][tid], sred[1][tid]),
                             fmaxf(sred[2][tid], sred[3][tid]));
            atomicMax((int*)(wsf + WS_ACT + c * 9 + tid), __float_as_int(mm));
        }
    } else {
        const int k = (blockIdx.x - 1024) * 4 + wid;
        float m = fmaxf(fabsf(w[lane * KSIZE + k]), fabsf(w[(lane + 64) * KSIZE + k]));
        for (int off = 32; off; off >>= 1) m = fmaxf(m, __shfl_down(m, off));
        if (lane == 0) wsf[WS_WSC + k] = m;
    }
}

// ---------------------------------------------------------------------------
// Kernel 2: scale + weight quantize -> int8, pre-swizzled (unchanged — validated R3/R4).
// ---------------------------------------------------------------------------
__global__ __launch_bounds__(576) void k_scale_wq(const float* __restrict__ w,
                                                  float* __restrict__ wsf,
                                                  char* __restrict__ wq_s) {
    __shared__ float ls[576];
    __shared__ float redA[9], redB[9];
    const int t = threadIdx.x, o = blockIdx.x;
    const int lane = t & 63, wid = t >> 6;
    const float a = wsf[WS_ACT + t];
    const float wv = wsf[WS_WSC + t];
    float s = sqrtf(a) / sqrtf(wv);
    if (s == 0.f) s = 1.f;
    ls[t] = s;
    float v1 = a / s;
    float v2 = wv * s;
    for (int off = 32; off; off >>= 1) {
        v1 = fmaxf(v1, __shfl_down(v1, off));
        v2 = fmaxf(v2, __shfl_down(v2, off));
    }
    if (lane == 0) { redA[wid] = v1; redB[wid] = v2; }
    __syncthreads();
    float ax = redA[0], aw = redB[0];
#pragma unroll
    for (int i = 1; i < 9; ++i) { ax = fmaxf(ax, redA[i]); aw = fmaxf(aw, redB[i]); }
    const float sx = ax > 0.f ? ax / 127.f : 1.f;
    const float sw = aw > 0.f ? aw / 127.f : 1.f;
    const int r = t >> 6, c = t & 63, ko = c * 9 + r;
    float q = rintf((w[o * KSIZE + ko] * ls[ko]) / sw);
    q = fminf(127.f, fmaxf(-127.f, q));
    const int qi = (int)q;
    const int fc = c >> 4;
    wq_s[r * 8192 + o * 64 + ((fc ^ SWZ(o)) << 4) + (c & 15)] = (char)qi;
    if (o == 0) {
        wsf[WS_XMUL + t] = 1.0f / (ls[ko] * sx);   // [r][c] layout
        if (t == 0) wsf[WS_SXSW] = sx * sw;
    }
}

// ---------------------------------------------------------------------------
// Kernel 3: barrier-free i8 implicit-GEMM conv, v2.
// Block = (b, oh): 512 threads = 8 waves; wave tile 16ow x 128o -> no A-work
// duplication across waves. Per chunk per thread: 16 coalesced dword loads,
// 16 one-FMA magic quantizes (clamp proven unnecessary), 3 v_perm packs/4el,
// 8 conflict-free ds_read_b128 of B, 8 MFMA. Block-uniform kh skip.
// ---------------------------------------------------------------------------
__global__ __launch_bounds__(512, 4) void k_gemm(const float* __restrict__ in,
                                                 const char* __restrict__ wq_s,
                                                 const float* __restrict__ wsf,
                                                 float* __restrict__ out) {
    __shared__ int4v Bl4[4608];        // 73728 B: 9 planes of [o=128][c=64] i8
    __shared__ float xml[576];
    char* Bl = (char*)Bl4;

    const int tid = threadIdx.x, lane = tid & 63, w = tid >> 6;
    // XCD swizzle: each XCD owns a 16-row oh band per batch (L2 input reuse).
    const int xcd = blockIdx.x & 7, idx = blockIdx.x >> 3;
    const int oh = xcd * 16 + (idx & 15);
    const int b = idx >> 4;
    const int l15 = lane & 15, fsel = lane >> 4;
    const int ow0 = w * 16 + l15;          // this lane's M index (A row)

    // ---- prologue staging (only barrier in the kernel) ----
#pragma unroll
    for (int i = 0; i < 9; ++i)
        async_cp16(wq_s + i * 8192 + tid * 16, Bl + i * 8192 + tid * 16);
    if (tid < 144)
        ((float4v*)xml)[tid] = ((const float4v*)(wsf + WS_XMUL))[tid];
    __syncthreads();

    const float* pb = in + ((size_t)b * CIN + fsel * 16) * (HW * HW);

    int4v acc[8];
#pragma unroll
    for (int nt = 0; nt < 8; ++nt) acc[nt] = (int4v){0, 0, 0, 0};

#pragma unroll
    for (int r = 0; r < 9; ++r) {
        const int kh = r / 3, kw = r - 3 * kh;
        const int h = oh + kh - 1;
        if (h >= 0 && h < HW) {            // block-uniform: skip whole chunk
            const int iw = ow0 + kw - 1;
            int iwc = iw;
            if (kw == 0) iwc = iw < 0 ? 0 : iw;
            if (kw == 2) iwc = iw > 127 ? 127 : iw;
            // ---- A loads: lanes 0..15 contiguous iw -> coalesced dwords ----
            const float* p = pb + h * HW + iwc;
            float v[16];
#pragma unroll
            for (int j = 0; j < 16; ++j) v[j] = p[j * (HW * HW)];
            // ---- per-lane scales: 4 broadcast ds_read_b128 ----
            const float* xp = xml + r * 64 + (fsel << 4);
            float4v xq[4];
#pragma unroll
            for (int d = 0; d < 4; ++d) xq[d] = *(const float4v*)(xp + d * 4);
            // ---- quantize: single fma (magic bias), 3 perm per 4 els ----
            uint pk[4];
#pragma unroll
            for (int d = 0; d < 4; ++d) {
                uint u[4];
#pragma unroll
                for (int j2 = 0; j2 < 4; ++j2)
                    u[j2] = __float_as_uint(fmaf(v[d * 4 + j2], xq[d][j2], MAGIC));
                const uint p01 = __builtin_amdgcn_perm(u[1], u[0], 0x0C0C0400u);
                const uint p23 = __builtin_amdgcn_perm(u[3], u[2], 0x0C0C0400u);
                pk[d] = __builtin_amdgcn_perm(p23, p01, 0x05040100u);
            }
            int4v af;
            if (kw != 1) {                 // zero the one OOB edge lane
                const uint msk = ((unsigned)iw < 128u) ? 0xFFFFFFFFu : 0u;
                af = (int4v){(int)(pk[0] & msk), (int)(pk[1] & msk),
                             (int)(pk[2] & msk), (int)(pk[3] & msk)};
            } else {
                af = (int4v){(int)pk[0], (int)pk[1], (int)pk[2], (int)pk[3]};
            }
            // ---- B frags (conflict-free swizzle) + 8 MFMA ----
#pragma unroll
            for (int nt = 0; nt < 8; ++nt) {
                const int br = nt * 16 + l15;
                const int4v bf = *(const int4v*)(Bl + r * 8192 + br * 64 +
                                                 ((fsel ^ SWZ(br)) << 4));
                acc[nt] = __builtin_amdgcn_mfma_i32_16x16x64_i8(af, bf, acc[nt], 0, 0, 0);
            }
        }
    }

    // ---- epilogue: row=(lane>>4)*4+reg -> ow, col=lane&15 -> o ----
    const float sxsw = wsf[WS_SXSW];
    const int owp = w * 16 + (fsel << 2);
#pragma unroll
    for (int nt = 0; nt < 8; ++nt) {
        const int o = nt * 16 + l15;
        float4v rv;
#pragma unroll
        for (int q = 0; q < 4; ++q) rv[q] = (float)acc[nt][q] * sxsw;
        *(float4v*)(out + ((size_t)(b * OC + o) * HW + oh) * HW + owp) = rv;
    }
}

// ---------------------------------------------------------------------------
extern "C" void kernel_launch(void* const* d_in, const int* in_sizes, int n_in,
                              void* d_out, int out_size, void* d_ws, size_t ws_size,
                              hipStream_t stream) {
    const float* in = (const float*)d_in[0];   // (16, 64, 128, 128) fp32
    const float* wt = (const float*)d_in[1];   // (128, 64, 3, 3) fp32
    float* out = (float*)d_out;                // (16, 128, 128, 128) fp32
    float* wsf = (float*)d_ws;
    char* wq_s = (char*)d_ws + WS_WQ_BYTE_OFF;

    k_absmax<<<dim3(1024 + 144), dim3(256), 0, stream>>>(in, wt, wsf);
    k_scale_wq<<<dim3(128), dim3(576), 0, stream>>>(wt, wsf, wq_s);
    k_gemm<<<dim3(BATCH * HW), dim3(512), 0, stream>>>(in, wq_s, wsf, out);
}